// Round 17
// baseline (61.646 us; speedup 1.0000x reference)
//
#include <hip/hip_runtime.h>
#include <hip/hip_bf16.h>
#include <math.h>

typedef unsigned short u16;
typedef unsigned int   u32;
typedef __attribute__((ext_vector_type(8))) short short8;
typedef __attribute__((ext_vector_type(4))) float f32x4;

// Problem constants
#define B_  4
#define C_  64
#define H_  128
#define W_  128
#define O_  64
#define HW_ (H_ * W_)

__device__ __forceinline__ u16 f2bf(float f) {
    __hip_bfloat16 h = __float2bfloat16(f);
    u16 u; __builtin_memcpy(&u, &h, 2); return u;
}
__device__ __forceinline__ u32 pkbf(float lo, float hi) {
    return ((u32)f2bf(hi) << 16) | (u32)f2bf(lo);
}
__device__ __forceinline__ float bflo(u32 v) { return __uint_as_float(v << 16); }
__device__ __forceinline__ float bfhi(u32 v) { return __uint_as_float(v & 0xffff0000u); }

// interp 8 channels (one uint4 = 8 bf16 per corner) -> packed uint4
__device__ __forceinline__ uint4 interp8(
    uint4 c00, uint4 c01, uint4 c10, uint4 c11,
    float wtx, float wty, float wtz, float wtw)
{
    const u32* q00 = (const u32*)&c00;
    const u32* q01 = (const u32*)&c01;
    const u32* q10 = (const u32*)&c10;
    const u32* q11 = (const u32*)&c11;
    u32 bw[4];
#pragma unroll
    for (int q = 0; q < 4; ++q) {
        float slo = bflo(q00[q]) * wtx;
        slo = fmaf(bflo(q01[q]), wty, slo);
        slo = fmaf(bflo(q10[q]), wtz, slo);
        slo = fmaf(bflo(q11[q]), wtw, slo);
        float shi = bfhi(q00[q]) * wtx;
        shi = fmaf(bfhi(q01[q]), wty, shi);
        shi = fmaf(bfhi(q10[q]), wtz, shi);
        shi = fmaf(bfhi(q11[q]), wtw, shi);
        bw[q] = pkbf(slo, shi);
    }
    uint4 v; __builtin_memcpy(&v, bw, 16);
    return v;
}

// -------------------------------------------------------------------------
// prep: blocks 0..1023   : transpose x (B,C,H,W) f32 -> xt (B,H,W,C) bf16
//       blocks 1024..1239: repack weight->Wb, ow|mw->OWb (A-frag order)
// K index convention: kidx = tap*64 + c  (tap-major, channel minor)
// A-frag (16x16x32): lane l holds A[o = l&15][k = ks*32 + (l>>4)*8 + j]
// -------------------------------------------------------------------------
__global__ __launch_bounds__(256) void prep(
    const float* __restrict__ x, const float* __restrict__ weight,
    const float* __restrict__ ow, const float* __restrict__ mw,
    u16* __restrict__ xt, u16* __restrict__ Wb, u16* __restrict__ OWb)
{
    int i = blockIdx.x, t = threadIdx.x;
    if (i < 1024) {                             // transpose
        __shared__ float tile[64][65];
        int lb = i >> 8;                        // 0..3
        int pix0 = (i & 255) << 6;
        const float* xb = x + ((size_t)lb << 20);
#pragma unroll
        for (int it = 0; it < 4; ++it) {
            int e = it * 256 + t;               // 0..1023
            int c = e >> 4;                     // channel 0..63
            int pl4 = (e & 15) << 2;            // pixel group of 4
            float4 v = *(const float4*)&xb[((size_t)c << 14) + pix0 + pl4];
            tile[c][pl4 + 0] = v.x;
            tile[c][pl4 + 1] = v.y;
            tile[c][pl4 + 2] = v.z;
            tile[c][pl4 + 3] = v.w;
        }
        __syncthreads();
        u16* xo = xt + ((((size_t)lb << 14) + pix0) << 6);
#pragma unroll
        for (int it = 0; it < 4; ++it) {
            int e = it * 256 + t;               // 0..1023
            int c4 = (e & 15) << 2;             // channel group of 4
            int pl = e >> 4;                    // pixel 0..63
            ushort4 v;
            v.x = f2bf(tile[c4 + 0][pl]);
            v.y = f2bf(tile[c4 + 1][pl]);
            v.z = f2bf(tile[c4 + 2][pl]);
            v.w = f2bf(tile[c4 + 3][pl]);
            *(ushort4*)&xo[((size_t)pl << 6) + c4] = v;
        }
    } else {
        int e = (i - 1024) * 256 + t;           // 0..55295
        if (e < 36864) {                        // Wb
            int j = e & 7, ln = (e >> 3) & 63;
            int ks = (e >> 9) % 18, ot = e / 9216;
            int o = ot * 16 + (ln & 15);
            int kidx = ks * 32 + ((ln >> 4) << 3) + j;
            int k = kidx >> 6, c = kidx & 63;
            Wb[e] = f2bf(weight[((size_t)(o * 64 + c)) * 9 + k]);
        } else {                                // OWb
            int e2 = e - 36864;
            int j = e2 & 7, ln = (e2 >> 3) & 63;
            int ks = (e2 >> 9) % 18, ot = e2 / 9216;
            int o = ot * 16 + (ln & 15);
            int kidx = ks * 32 + ((ln >> 4) << 3) + j;
            int k = kidx >> 6, c = kidx & 63;
            float v = 0.0f;
            if (o < 18)      v = ow[((size_t)(o * 64 + c)) * 9 + k];
            else if (o < 27) v = mw[((size_t)((o - 18) * 64 + c)) * 9 + k];
            OWb[e2] = f2bf(v);
        }
    }
}

// -------------------------------------------------------------------------
// conv_off: K1 + bilinear-param setup ONLY. Block = 16 pixels, 2 waves
// (wave = otile). K1 B-frags loaded DIRECT from global xt (r8-verified
// coalesced pattern: 64B segments), 9-load batches pinned by sched_barrier.
// Result: packed (corner positions | bf16 weights) uint4 per (tap,pixel)
// -> global pk stream (coalesced). LDS = param only (1.7 KB).
// -------------------------------------------------------------------------
__global__ __launch_bounds__(128, 6) void conv_off(
    const u16* __restrict__ xt, const u16* __restrict__ OWb,
    const float* __restrict__ ob, const float* __restrict__ mb,
    uint4* __restrict__ pk)
{
    __shared__ float param[27][16];

    const int t = threadIdx.x;
    const int lane = t & 63;
    const int wv = t >> 6;          // otile 0..1
    const int mypix = lane & 15;
    const int hi = lane >> 4;

    int bid0 = blockIdx.x;          // 4096 blocks
    const int bid = (bid0 & 7) * 512 + (bid0 >> 3);   // XCD swizzle (bijective)
    const int lb = bid >> 10;
    const int pix0 = (bid & 1023) << 4;
    const int h  = pix0 >> 7;
    const int w0 = pix0 & 127;

    const u16* xtb = xt + ((size_t)lb << 20);

    // ---- K1: 2 batches of 9 in-flight loads, dual accumulators ----
    f32x4 k1a = {0.f, 0.f, 0.f, 0.f};
    f32x4 k1b = {0.f, 0.f, 0.f, 0.f};
#pragma unroll
    for (int half = 0; half < 2; ++half) {
        uint4 raw[9];
#pragma unroll
        for (int q = 0; q < 9; ++q) {
            int ks = half * 9 + q;
            int tap = ks >> 1;
            int ky = tap / 3, kx = tap - 3 * ky;
            int y  = h - 1 + ky;
            int xx = w0 + mypix - 1 + kx;
            int idx = ((y & 127) << 7) + (xx & 127);    // wrapped -> safe
            raw[q] = *(const uint4*)(xtb + ((size_t)idx << 6) + ((ks & 1) << 5) + (hi << 3));
        }
        __builtin_amdgcn_sched_barrier(0);
#pragma unroll
        for (int q = 0; q < 9; ++q) {
            int ks = half * 9 + q;
            int tap = ks >> 1;
            int ky = tap / 3, kx = tap - 3 * ky;
            int y  = h - 1 + ky;
            int xx = w0 + mypix - 1 + kx;
            bool valid = ((unsigned)y < 128u) && ((unsigned)xx < 128u);
            uint4 rw = raw[q];
            rw.x = valid ? rw.x : 0u;
            rw.y = valid ? rw.y : 0u;
            rw.z = valid ? rw.z : 0u;
            rw.w = valid ? rw.w : 0u;
            short8 bfr;
            __builtin_memcpy(&bfr, &rw, 16);
            short8 wa = ((const short8*)OWb)[(wv * 18 + ks) * 64 + lane];
            if (half == 0)
                k1a = __builtin_amdgcn_mfma_f32_16x16x32_bf16(wa, bfr, k1a, 0, 0, 0);
            else
                k1b = __builtin_amdgcn_mfma_f32_16x16x32_bf16(wa, bfr, k1b, 0, 0, 0);
        }
    }
#pragma unroll
    for (int r = 0; r < 4; ++r) {
        int oc = (wv << 4) + (hi << 2) + r;
        float v = k1a[r] + k1b[r];
        if (oc < 18) {
            param[oc][mypix] = v + ob[oc];
        } else if (oc < 27) {
            float s = v + mb[oc - 18];
            param[oc][mypix] = 2.0f / (1.0f + __expf(-s));
        }
    }
    __syncthreads();

    // ---- st1: bilinear corner positions + weights -> global pk ----
    for (int p = t; p < 144; p += 128) {
        int tap = p >> 4, pixl = p & 15;
        int ky = tap / 3, kx = tap - 3 * ky;
        float dy = param[2 * tap][pixl];
        float dx = param[2 * tap + 1][pixl];
        float m  = param[18 + tap][pixl];
        float py = (float)(h - 1 + ky) + dy;
        float px = (float)(w0 + pixl - 1 + kx) + dx;
        float y0f = floorf(py), x0f = floorf(px);
        float fy = py - y0f, fx = px - x0f;
        int y0 = (int)y0f, x0 = (int)x0f;
        int y1 = y0 + 1, x1 = x0 + 1;
        bool vy0 = (unsigned)y0 < (unsigned)H_;
        bool vy1 = (unsigned)y1 < (unsigned)H_;
        bool vx0 = (unsigned)x0 < (unsigned)W_;
        bool vx1 = (unsigned)x1 < (unsigned)W_;
        float w00 = (1.f - fy) * (1.f - fx) * m; if (!(vy0 && vx0)) w00 = 0.f;
        float w01 = (1.f - fy) * fx          * m; if (!(vy0 && vx1)) w01 = 0.f;
        float w10 = fy * (1.f - fx)          * m; if (!(vy1 && vx0)) w10 = 0.f;
        float w11 = fy * fx                   * m; if (!(vy1 && vx1)) w11 = 0.f;
        int y0c = min(max(y0, 0), H_ - 1);
        int y1c = min(max(y1, 0), H_ - 1);
        int x0c = min(max(x0, 0), W_ - 1);
        int x1c = min(max(x1, 0), W_ - 1);
        pk[(size_t)bid * 144 + p] = make_uint4(
            (u32)((y0c << 7) + x0c) | ((u32)((y0c << 7) + x1c) << 16),
            (u32)((y1c << 7) + x0c) | ((u32)((y1c << 7) + x1c) << 16),
            (u32)f2bf(w00) | ((u32)f2bf(w01) << 16),
            (u32)f2bf(w10) | ((u32)f2bf(w11) << 16));
    }
}

// -------------------------------------------------------------------------
// dcn: gather + main contraction ONLY. Block = 16 pixels, 4 waves, ONE
// barrier. LDS = S only (18.4 KB) -> 8 blocks/CU = 32 waves (chip max).
//   P2 : deformable gather, uint4/lane (8ch), 2-task batch (8 x 16B corner
//        loads pinned via sched_barrier); params from global pk (L1 bcast)
//   P3 : wave = otile: 18 swizzled ds_read_b128 + A-frags + MFMA (2 accs)
// -------------------------------------------------------------------------
__global__ __launch_bounds__(256, 8) void dcn(
    const u16* __restrict__ xt, const u16* __restrict__ Wb,
    const uint4* __restrict__ pk, float* __restrict__ out)
{
    __shared__ __align__(16) u16 S[16][576];     // 18432 B, group-XOR swizzled

    const int t = threadIdx.x;
    const int lane = t & 63;
    const int wv = t >> 6;          // 0..3

    int bid0 = blockIdx.x;          // 4096 blocks
    const int bid = (bid0 & 7) * 512 + (bid0 >> 3);   // XCD swizzle (bijective)
    const int lb = bid >> 10;
    const int pix0 = (bid & 1023) << 4;

    const u16* xtb = xt + ((size_t)lb << 20);
    const char* xb8 = (const char*)xtb;
    const uint4* pkb = pk + (size_t)bid * 144;

    // ---- P2: deformable gather, uint4/lane (8ch), 2-task batch ----
#pragma unroll
    for (int ii = 0; ii < 2; ++ii) {
        int e0 = ii * 512 + t;
        int e1 = e0 + 256;
        int u0 = e0 >> 3, o0 = e0 & 7;
        int u1 = e1 >> 3, o1 = e1 & 7;
        uint4 q0 = pkb[u0];
        uint4 q1 = pkb[u1];
        int co0 = o0 << 4, co1 = o1 << 4;
        uint4 a00 = *(const uint4*)(xb8 + ((q0.x & 0xffffu) << 7) + co0);
        uint4 a01 = *(const uint4*)(xb8 + ((q0.x >> 16) << 7) + co0);
        uint4 a10 = *(const uint4*)(xb8 + ((q0.y & 0xffffu) << 7) + co0);
        uint4 a11 = *(const uint4*)(xb8 + ((q0.y >> 16) << 7) + co0);
        uint4 b00 = *(const uint4*)(xb8 + ((q1.x & 0xffffu) << 7) + co1);
        uint4 b01 = *(const uint4*)(xb8 + ((q1.x >> 16) << 7) + co1);
        uint4 b10 = *(const uint4*)(xb8 + ((q1.y & 0xffffu) << 7) + co1);
        uint4 b11 = *(const uint4*)(xb8 + ((q1.y >> 16) << 7) + co1);
        __builtin_amdgcn_sched_barrier(0);
        {
            int k = u0 >> 4, pixl = u0 & 15;
            uint4 v = interp8(a00, a01, a10, a11,
                              bflo(q0.z), bfhi(q0.z), bflo(q0.w), bfhi(q0.w));
            *(uint4*)&S[pixl][k * 64 + ((o0 ^ (pixl & 7)) << 3)] = v;
        }
        {
            int k = u1 >> 4, pixl = u1 & 15;
            uint4 v = interp8(b00, b01, b10, b11,
                              bflo(q1.z), bfhi(q1.z), bflo(q1.w), bfhi(q1.w));
            *(uint4*)&S[pixl][k * 64 + ((o1 ^ (pixl & 7)) << 3)] = v;
        }
    }
    if (t < 128) {                  // tail: units 128..143 (tap 8)
        int e = 1024 + t;
        int u = e >> 3, oct = e & 7;
        int pixl = u & 15;
        uint4 q = pkb[u];
        int co = oct << 4;
        uint4 c00 = *(const uint4*)(xb8 + ((q.x & 0xffffu) << 7) + co);
        uint4 c01 = *(const uint4*)(xb8 + ((q.x >> 16) << 7) + co);
        uint4 c10 = *(const uint4*)(xb8 + ((q.y & 0xffffu) << 7) + co);
        uint4 c11 = *(const uint4*)(xb8 + ((q.y >> 16) << 7) + co);
        uint4 v = interp8(c00, c01, c10, c11,
                          bflo(q.z), bfhi(q.z), bflo(q.w), bfhi(q.w));
        *(uint4*)&S[pixl][8 * 64 + ((oct ^ (pixl & 7)) << 3)] = v;
    }
    __syncthreads();

    // ---- P3: main contraction, wave = otile; dual accumulators ----
    {
        f32x4 acca = {0.f, 0.f, 0.f, 0.f};
        f32x4 accb = {0.f, 0.f, 0.f, 0.f};
        int brow = lane & 15;
        int hi = lane >> 4;
        int swz = (brow & 7) << 3;
#pragma unroll
        for (int kp = 0; kp < 9; ++kp) {
            int ks0 = kp * 2, ks1 = kp * 2 + 1;
            short8 b0 = *(const short8*)&S[brow][kp * 64 + ((hi << 3) ^ swz)];
            short8 b1 = *(const short8*)&S[brow][kp * 64 + ((32 + (hi << 3)) ^ swz)];
            short8 a0 = ((const short8*)Wb)[(wv * 18 + ks0) * 64 + lane];
            short8 a1 = ((const short8*)Wb)[(wv * 18 + ks1) * 64 + lane];
            acca = __builtin_amdgcn_mfma_f32_16x16x32_bf16(a0, b0, acca, 0, 0, 0);
            accb = __builtin_amdgcn_mfma_f32_16x16x32_bf16(a1, b1, accb, 0, 0, 0);
        }
        float* op = out + ((size_t)lb << 20) + pix0;
#pragma unroll
        for (int r = 0; r < 4; ++r) {
            int o = wv * 16 + (hi << 2) + r;
            op[((size_t)o << 14) + brow] = acca[r] + accb[r];
        }
    }
}

// -------------------------------------------------------------------------
extern "C" void kernel_launch(void* const* d_in, const int* in_sizes, int n_in,
                              void* d_out, int out_size, void* d_ws, size_t ws_size,
                              hipStream_t stream)
{
    const float* x        = (const float*)d_in[0];
    const float* offset_w = (const float*)d_in[1];
    const float* offset_b = (const float*)d_in[2];
    const float* mod_w    = (const float*)d_in[3];
    const float* mod_b    = (const float*)d_in[4];
    const float* weight   = (const float*)d_in[5];
    float* out = (float*)d_out;

    // Workspace layout (~17.9 MiB of the ~256 MiB ws):
    //   pk : 4096 blocks * 144 units * 16 B = 9,437,184 B (16B-aligned first)
    //   Wb : 36864 u16 | OWb : 18432 u16 | xt : 4,194,304 u16
    uint4* pk = (uint4*)d_ws;
    u16* Wb  = (u16*)((char*)d_ws + 9437184);
    u16* OWb = Wb + 36864;
    u16* xt  = OWb + 18432;

    prep<<<1240, 256, 0, stream>>>(x, weight, offset_w, mod_w, xt, Wb, OWb);
    conv_off<<<4096, 128, 0, stream>>>(xt, OWb, offset_b, mod_b, pk);
    dcn<<<4096, 256, 0, stream>>>(xt, Wb, pk, out);
}

// Round 18
// 56.553 us; speedup vs baseline: 1.0901x; 1.0901x over previous
//
#include <hip/hip_runtime.h>
#include <hip/hip_bf16.h>
#include <math.h>

typedef unsigned short u16;
typedef unsigned int   u32;
typedef __attribute__((ext_vector_type(8))) short short8;
typedef __attribute__((ext_vector_type(4))) float f32x4;

// Problem constants
#define B_  4
#define C_  64
#define H_  128
#define W_  128
#define O_  64
#define HW_ (H_ * W_)

__device__ __forceinline__ u16 f2bf(float f) {
    __hip_bfloat16 h = __float2bfloat16(f);
    u16 u; __builtin_memcpy(&u, &h, 2); return u;
}
__device__ __forceinline__ float bf2f(u16 u) {
    return __uint_as_float((u32)u << 16);
}
__device__ __forceinline__ u32 pkbf(float lo, float hi) {
    return ((u32)f2bf(hi) << 16) | (u32)f2bf(lo);
}
__device__ __forceinline__ float bflo(u32 v) { return __uint_as_float(v << 16); }
__device__ __forceinline__ float bfhi(u32 v) { return __uint_as_float(v & 0xffff0000u); }

// interp 8 channels (one uint4 = 8 bf16 per corner) -> packed uint4
__device__ __forceinline__ uint4 interp8(
    uint4 c00, uint4 c01, uint4 c10, uint4 c11,
    float wtx, float wty, float wtz, float wtw)
{
    const u32* q00 = (const u32*)&c00;
    const u32* q01 = (const u32*)&c01;
    const u32* q10 = (const u32*)&c10;
    const u32* q11 = (const u32*)&c11;
    u32 bw[4];
#pragma unroll
    for (int q = 0; q < 4; ++q) {
        float slo = bflo(q00[q]) * wtx;
        slo = fmaf(bflo(q01[q]), wty, slo);
        slo = fmaf(bflo(q10[q]), wtz, slo);
        slo = fmaf(bflo(q11[q]), wtw, slo);
        float shi = bfhi(q00[q]) * wtx;
        shi = fmaf(bfhi(q01[q]), wty, shi);
        shi = fmaf(bfhi(q10[q]), wtz, shi);
        shi = fmaf(bfhi(q11[q]), wtw, shi);
        bw[q] = pkbf(slo, shi);
    }
    uint4 v; __builtin_memcpy(&v, bw, 16);
    return v;
}

// -------------------------------------------------------------------------
// prep: blocks 0..1023   : transpose x (B,C,H,W) f32 -> xt (B,H,W,C) bf16
//       blocks 1024..1239: repack weight->Wb, ow|mw->OWb (A-frag order)
// K index convention: kidx = tap*64 + c  (tap-major, channel minor)
// A-frag (16x16x32): lane l holds A[o = l&15][k = ks*32 + (l>>4)*8 + j]
// -------------------------------------------------------------------------
__global__ __launch_bounds__(256) void prep(
    const float* __restrict__ x, const float* __restrict__ weight,
    const float* __restrict__ ow, const float* __restrict__ mw,
    u16* __restrict__ xt, u16* __restrict__ Wb, u16* __restrict__ OWb)
{
    int i = blockIdx.x, t = threadIdx.x;
    if (i < 1024) {                             // transpose
        __shared__ float tile[64][65];
        int lb = i >> 8;                        // 0..3
        int pix0 = (i & 255) << 6;
        const float* xb = x + ((size_t)lb << 20);
#pragma unroll
        for (int it = 0; it < 4; ++it) {
            int e = it * 256 + t;               // 0..1023
            int c = e >> 4;                     // channel 0..63
            int pl4 = (e & 15) << 2;            // pixel group of 4
            float4 v = *(const float4*)&xb[((size_t)c << 14) + pix0 + pl4];
            tile[c][pl4 + 0] = v.x;
            tile[c][pl4 + 1] = v.y;
            tile[c][pl4 + 2] = v.z;
            tile[c][pl4 + 3] = v.w;
        }
        __syncthreads();
        u16* xo = xt + ((((size_t)lb << 14) + pix0) << 6);
#pragma unroll
        for (int it = 0; it < 4; ++it) {
            int e = it * 256 + t;               // 0..1023
            int c4 = (e & 15) << 2;             // channel group of 4
            int pl = e >> 4;                    // pixel 0..63
            ushort4 v;
            v.x = f2bf(tile[c4 + 0][pl]);
            v.y = f2bf(tile[c4 + 1][pl]);
            v.z = f2bf(tile[c4 + 2][pl]);
            v.w = f2bf(tile[c4 + 3][pl]);
            *(ushort4*)&xo[((size_t)pl << 6) + c4] = v;
        }
    } else {
        int e = (i - 1024) * 256 + t;           // 0..55295
        if (e < 36864) {                        // Wb
            int j = e & 7, ln = (e >> 3) & 63;
            int ks = (e >> 9) % 18, ot = e / 9216;
            int o = ot * 16 + (ln & 15);
            int kidx = ks * 32 + ((ln >> 4) << 3) + j;
            int k = kidx >> 6, c = kidx & 63;
            Wb[e] = f2bf(weight[((size_t)(o * 64 + c)) * 9 + k]);
        } else {                                // OWb
            int e2 = e - 36864;
            int j = e2 & 7, ln = (e2 >> 3) & 63;
            int ks = (e2 >> 9) % 18, ot = e2 / 9216;
            int o = ot * 16 + (ln & 15);
            int kidx = ks * 32 + ((ln >> 4) << 3) + j;
            int k = kidx >> 6, c = kidx & 63;
            float v = 0.0f;
            if (o < 18)      v = ow[((size_t)(o * 64 + c)) * 9 + k];
            else if (o < 27) v = mw[((size_t)((o - 18) * 64 + c)) * 9 + k];
            OWb[e2] = f2bf(v);
        }
    }
}

// -------------------------------------------------------------------------
// fused_dcn: r14 monolith with P0 DELETED. Block = 16 pixels, 4 waves,
// 3 barriers:
//   K1 : all 4 waves = (otile, K-half): 9 direct-global im2col loads
//        (batched, sched_barrier-pinned) + 9 MFMAs -> kp partials in a
//        4KB scratch OVERLAID on the then-dead S buffer
//   st1: threads 0..143: combine K-halves + bias/sigmoid, bilinear corner
//        byte-offsets (int4) + bf16 weights -> pwp/pww
//   P2 : deformable gather, uint4/lane (8ch), 4-task batch (16 x 16B
//        corner loads pinned in flight) -> S swizzled; 128-thr tail
//   P3 : wave = otile: swizzled ds_read_b128 + A-frags + MFMA (dual acc)
// LDS: S 18432 (kp overlay) + pwp 2304 + pww 1152 = 21888 B -> 6 blocks/CU
// at launch_bounds(256,6) (VGPR cap 85; 4-task P2 needs ~80).
// -------------------------------------------------------------------------
__global__ __launch_bounds__(256, 6) void fused_dcn(
    const u16* __restrict__ xt,
    const u16* __restrict__ Wb, const u16* __restrict__ OWb,
    const float* __restrict__ ob, const float* __restrict__ mb,
    float* __restrict__ out)
{
    __shared__ __align__(16) u16 S[16][576];     // 18432 B; kp f32[1024] overlay
    __shared__ __align__(16) int4    pwp[144];   //  2304 B corner byte offsets
    __shared__ __align__(8)  ushort4 pww[144];   //  1152 B bf16 bilinear*mask wts

    float* kpf = (float*)S;         // [ (kh*2+ot) ][ row 0..15 ][ pix 0..15 ]

    const int t = threadIdx.x;
    const int lane = t & 63;
    const int wv = t >> 6;          // 0..3
    const int mypix = lane & 15;
    const int hi = lane >> 4;       // channel octet (within 32-ch half in K1)

    int bid0 = blockIdx.x;          // 4096 blocks
    const int bid = (bid0 & 7) * 512 + (bid0 >> 3);   // XCD swizzle (bijective)
    const int lb = bid >> 10;       // batch
    const int pix0 = (bid & 1023) << 4;
    const int h  = pix0 >> 7;       // 16 pixels share one row
    const int w0 = pix0 & 127;

    const u16* xtb = xt + ((size_t)lb << 20);
    const char* xb8 = (const char*)xtb;

    // ---- K1: offset/mask conv; wave = (otile, K-half); direct-global ----
    {
        const int ot = wv & 1, kh = wv >> 1;
        f32x4 k1 = {0.f, 0.f, 0.f, 0.f};
        uint4 raw[9];
#pragma unroll
        for (int q = 0; q < 9; ++q) {
            int ks = kh * 9 + q;
            int tap = ks >> 1;
            int ky = tap / 3, kx = tap - 3 * ky;
            int y  = h - 1 + ky;
            int xx = w0 + mypix - 1 + kx;
            int idx = ((y & 127) << 7) + (xx & 127);    // wrapped -> safe
            raw[q] = *(const uint4*)(xtb + ((size_t)idx << 6) + ((ks & 1) << 5) + (hi << 3));
        }
        __builtin_amdgcn_sched_barrier(0);
#pragma unroll
        for (int q = 0; q < 9; ++q) {
            int ks = kh * 9 + q;
            int tap = ks >> 1;
            int ky = tap / 3, kx = tap - 3 * ky;
            int y  = h - 1 + ky;
            int xx = w0 + mypix - 1 + kx;
            bool valid = ((unsigned)y < 128u) && ((unsigned)xx < 128u);
            uint4 rw = raw[q];
            rw.x = valid ? rw.x : 0u;
            rw.y = valid ? rw.y : 0u;
            rw.z = valid ? rw.z : 0u;
            rw.w = valid ? rw.w : 0u;
            short8 bfr;
            __builtin_memcpy(&bfr, &rw, 16);
            short8 wa = ((const short8*)OWb)[(ot * 18 + ks) * 64 + lane];
            k1 = __builtin_amdgcn_mfma_f32_16x16x32_bf16(wa, bfr, k1, 0, 0, 0);
        }
        // kp partial: [kh*2+ot][hi*4+r][mypix]
#pragma unroll
        for (int r = 0; r < 4; ++r)
            kpf[((kh << 1) + ot) * 256 + ((hi << 2) + r) * 16 + mypix] = k1[r];
    }
    __syncthreads();

    // ---- st1: combine K-halves + bias/sigmoid, bilinear params ----
    if (t < 144) {
        int tap = t >> 4, pix = t & 15;
        int ky = tap / 3, kx = tap - 3 * ky;
        int ocy = 2 * tap, ocx = 2 * tap + 1, ocm = 18 + tap;
        float dy = kpf[((ocy >> 4)) * 256 + (ocy & 15) * 16 + pix]
                 + kpf[512 + ((ocy >> 4)) * 256 + (ocy & 15) * 16 + pix] + ob[ocy];
        float dx = kpf[((ocx >> 4)) * 256 + (ocx & 15) * 16 + pix]
                 + kpf[512 + ((ocx >> 4)) * 256 + (ocx & 15) * 16 + pix] + ob[ocx];
        float sm = kpf[256 + (ocm - 16) * 16 + pix]
                 + kpf[512 + 256 + (ocm - 16) * 16 + pix] + mb[tap];
        float m  = 2.0f / (1.0f + __expf(-sm));
        float py = (float)(h - 1 + ky) + dy;
        float px = (float)(w0 + pix - 1 + kx) + dx;
        float y0f = floorf(py), x0f = floorf(px);
        float fy = py - y0f, fx = px - x0f;
        int y0 = (int)y0f, x0 = (int)x0f;
        int y1 = y0 + 1, x1 = x0 + 1;
        bool vy0 = (unsigned)y0 < (unsigned)H_;
        bool vy1 = (unsigned)y1 < (unsigned)H_;
        bool vx0 = (unsigned)x0 < (unsigned)W_;
        bool vx1 = (unsigned)x1 < (unsigned)W_;
        float w00 = (1.f - fy) * (1.f - fx) * m; if (!(vy0 && vx0)) w00 = 0.f;
        float w01 = (1.f - fy) * fx          * m; if (!(vy0 && vx1)) w01 = 0.f;
        float w10 = fy * (1.f - fx)          * m; if (!(vy1 && vx0)) w10 = 0.f;
        float w11 = fy * fx                   * m; if (!(vy1 && vx1)) w11 = 0.f;
        int y0c = min(max(y0, 0), H_ - 1);
        int y1c = min(max(y1, 0), H_ - 1);
        int x0c = min(max(x0, 0), W_ - 1);
        int x1c = min(max(x1, 0), W_ - 1);
        // byte offsets into xt batch slab: pos (elem) * 64ch * 2B = pos<<7
        pwp[t] = make_int4(((y0c << 7) + x0c) << 7, ((y0c << 7) + x1c) << 7,
                           ((y1c << 7) + x0c) << 7, ((y1c << 7) + x1c) << 7);
        pww[t] = make_ushort4(f2bf(w00), f2bf(w01), f2bf(w10), f2bf(w11));
    }
    __syncthreads();

    // ---- P2: deformable gather, uint4/lane (8ch), 4-task batch ----
    // oct = t&7; unit u_i = (t>>3) + 32*i covers units 0..127 (taps 0..7);
    // 16 x 16B loads pinned in flight, then 4 x interp8 + swizzled store.
    {
        const int oct = t & 7;
        const int ub  = t >> 3;
        int4 ofs0 = pwp[ub];       ushort4 wq0 = pww[ub];
        int4 ofs1 = pwp[ub + 32];  ushort4 wq1 = pww[ub + 32];
        int4 ofs2 = pwp[ub + 64];  ushort4 wq2 = pww[ub + 64];
        int4 ofs3 = pwp[ub + 96];  ushort4 wq3 = pww[ub + 96];
        const int co = oct << 4;
        uint4 a00 = *(const uint4*)(xb8 + ofs0.x + co);
        uint4 a01 = *(const uint4*)(xb8 + ofs0.y + co);
        uint4 a10 = *(const uint4*)(xb8 + ofs0.z + co);
        uint4 a11 = *(const uint4*)(xb8 + ofs0.w + co);
        uint4 b00 = *(const uint4*)(xb8 + ofs1.x + co);
        uint4 b01 = *(const uint4*)(xb8 + ofs1.y + co);
        uint4 b10 = *(const uint4*)(xb8 + ofs1.z + co);
        uint4 b11 = *(const uint4*)(xb8 + ofs1.w + co);
        uint4 c00 = *(const uint4*)(xb8 + ofs2.x + co);
        uint4 c01 = *(const uint4*)(xb8 + ofs2.y + co);
        uint4 c10 = *(const uint4*)(xb8 + ofs2.z + co);
        uint4 c11 = *(const uint4*)(xb8 + ofs2.w + co);
        uint4 d00 = *(const uint4*)(xb8 + ofs3.x + co);
        uint4 d01 = *(const uint4*)(xb8 + ofs3.y + co);
        uint4 d10 = *(const uint4*)(xb8 + ofs3.z + co);
        uint4 d11 = *(const uint4*)(xb8 + ofs3.w + co);
        __builtin_amdgcn_sched_barrier(0);
        {
            int k = ub >> 4, pixl = ub & 15;
            uint4 v = interp8(a00, a01, a10, a11,
                              bf2f(wq0.x), bf2f(wq0.y), bf2f(wq0.z), bf2f(wq0.w));
            *(uint4*)&S[pixl][k * 64 + ((oct ^ (pixl & 7)) << 3)] = v;
        }
        {
            int u1 = ub + 32;
            int k = u1 >> 4, pixl = u1 & 15;
            uint4 v = interp8(b00, b01, b10, b11,
                              bf2f(wq1.x), bf2f(wq1.y), bf2f(wq1.z), bf2f(wq1.w));
            *(uint4*)&S[pixl][k * 64 + ((oct ^ (pixl & 7)) << 3)] = v;
        }
        {
            int u2 = ub + 64;
            int k = u2 >> 4, pixl = u2 & 15;
            uint4 v = interp8(c00, c01, c10, c11,
                              bf2f(wq2.x), bf2f(wq2.y), bf2f(wq2.z), bf2f(wq2.w));
            *(uint4*)&S[pixl][k * 64 + ((oct ^ (pixl & 7)) << 3)] = v;
        }
        {
            int u3 = ub + 96;
            int k = u3 >> 4, pixl = u3 & 15;
            uint4 v = interp8(d00, d01, d10, d11,
                              bf2f(wq3.x), bf2f(wq3.y), bf2f(wq3.z), bf2f(wq3.w));
            *(uint4*)&S[pixl][k * 64 + ((oct ^ (pixl & 7)) << 3)] = v;
        }
    }
    if (t < 128) {                  // tail: units 128..143 (tap 8)
        int e = 1024 + t;
        int u = e >> 3, oct = e & 7;
        int pixl = u & 15;
        int4    ofs = pwp[u]; ushort4 wq = pww[u];
        uint4 c00 = *(const uint4*)(xb8 + ofs.x + (oct << 4));
        uint4 c01 = *(const uint4*)(xb8 + ofs.y + (oct << 4));
        uint4 c10 = *(const uint4*)(xb8 + ofs.z + (oct << 4));
        uint4 c11 = *(const uint4*)(xb8 + ofs.w + (oct << 4));
        uint4 v = interp8(c00, c01, c10, c11,
                          bf2f(wq.x), bf2f(wq.y), bf2f(wq.z), bf2f(wq.w));
        *(uint4*)&S[pixl][8 * 64 + ((oct ^ (pixl & 7)) << 3)] = v;
    }
    __syncthreads();

    // ---- P3: main contraction, wave = otile; dual accumulators ----
    {
        f32x4 acca = {0.f, 0.f, 0.f, 0.f};
        f32x4 accb = {0.f, 0.f, 0.f, 0.f};
        int brow = lane & 15;
        int hi2 = lane >> 4;
        int swz = (brow & 7) << 3;
#pragma unroll
        for (int kp = 0; kp < 9; ++kp) {
            int ks0 = kp * 2, ks1 = kp * 2 + 1;
            short8 b0 = *(const short8*)&S[brow][kp * 64 + ((hi2 << 3) ^ swz)];
            short8 b1 = *(const short8*)&S[brow][kp * 64 + ((32 + (hi2 << 3)) ^ swz)];
            short8 a0 = ((const short8*)Wb)[(wv * 18 + ks0) * 64 + lane];
            short8 a1 = ((const short8*)Wb)[(wv * 18 + ks1) * 64 + lane];
            acca = __builtin_amdgcn_mfma_f32_16x16x32_bf16(a0, b0, acca, 0, 0, 0);
            accb = __builtin_amdgcn_mfma_f32_16x16x32_bf16(a1, b1, accb, 0, 0, 0);
        }
        float* op = out + ((size_t)lb << 20) + pix0;
#pragma unroll
        for (int r = 0; r < 4; ++r) {
            int o = wv * 16 + (hi2 << 2) + r;
            op[((size_t)o << 14) + brow] = acca[r] + accb[r];
        }
    }
}

// -------------------------------------------------------------------------
extern "C" void kernel_launch(void* const* d_in, const int* in_sizes, int n_in,
                              void* d_out, int out_size, void* d_ws, size_t ws_size,
                              hipStream_t stream)
{
    const float* x        = (const float*)d_in[0];
    const float* offset_w = (const float*)d_in[1];
    const float* offset_b = (const float*)d_in[2];
    const float* mod_w    = (const float*)d_in[3];
    const float* mod_b    = (const float*)d_in[4];
    const float* weight   = (const float*)d_in[5];
    float* out = (float*)d_out;

    // Workspace (u16), total ~8.1 MiB:
    //   Wb : 36864 | OWb : 18432 | xt : 4 batches * HW * C = 4,194,304
    u16* Wb  = (u16*)d_ws;
    u16* OWb = Wb + 36864;
    u16* xt  = OWb + 18432;

    prep<<<1240, 256, 0, stream>>>(x, weight, offset_w, mod_w, xt, Wb, OWb);
    fused_dcn<<<4096, 256, 0, stream>>>(xt, Wb, OWb, offset_b, mod_b, out);
}

// Round 19
// 43.899 us; speedup vs baseline: 1.4043x; 1.2883x over previous
//
#include <hip/hip_runtime.h>
#include <hip/hip_bf16.h>
#include <math.h>

typedef unsigned short u16;
typedef unsigned int   u32;
typedef __attribute__((ext_vector_type(8))) short short8;
typedef __attribute__((ext_vector_type(4))) float f32x4;
typedef __attribute__((ext_vector_type(2))) float f32x2;

// Problem constants
#define B_  4
#define C_  64
#define H_  128
#define W_  128
#define O_  64
#define HW_ (H_ * W_)

__device__ __forceinline__ u16 f2bf(float f) {
    __hip_bfloat16 h = __float2bfloat16(f);
    u16 u; __builtin_memcpy(&u, &h, 2); return u;
}
__device__ __forceinline__ float bf2f(u16 u) {
    return __uint_as_float((u32)u << 16);
}
__device__ __forceinline__ u32 pkbf(float lo, float hi) {
    return ((u32)f2bf(hi) << 16) | (u32)f2bf(lo);
}
__device__ __forceinline__ float bflo(u32 v) { return __uint_as_float(v << 16); }
__device__ __forceinline__ float bfhi(u32 v) { return __uint_as_float(v & 0xffff0000u); }

// unpack u32 (2 bf16) -> f32x2 {lo, hi}
__device__ __forceinline__ f32x2 up2(u32 v) {
    f32x2 r;
    r.x = __uint_as_float(v << 16);
    r.y = __uint_as_float(v & 0xffff0000u);
    return r;
}

// interp 8 channels (one uint4 = 8 bf16 per corner) -> packed uint4.
// Packed-f32 math: per u32, 1 pk_mul + 3 pk_fma (v_pk_fma_f32) instead of
// 2 mul + 6 fma.
__device__ __forceinline__ uint4 interp8(
    uint4 c00, uint4 c01, uint4 c10, uint4 c11,
    float wtx, float wty, float wtz, float wtw)
{
    const u32* q00 = (const u32*)&c00;
    const u32* q01 = (const u32*)&c01;
    const u32* q10 = (const u32*)&c10;
    const u32* q11 = (const u32*)&c11;
    f32x2 w0 = {wtx, wtx}, w1 = {wty, wty}, w2 = {wtz, wtz}, w3 = {wtw, wtw};
    u32 bw[4];
#pragma unroll
    for (int q = 0; q < 4; ++q) {
        f32x2 s = up2(q00[q]) * w0;
        s = __builtin_elementwise_fma(up2(q01[q]), w1, s);
        s = __builtin_elementwise_fma(up2(q10[q]), w2, s);
        s = __builtin_elementwise_fma(up2(q11[q]), w3, s);
        bw[q] = pkbf(s.x, s.y);
    }
    uint4 v; __builtin_memcpy(&v, bw, 16);
    return v;
}

// -------------------------------------------------------------------------
// prep: blocks 0..1023   : transpose x (B,C,H,W) f32 -> xt (B,H,W,C) bf16
//       blocks 1024..1239: repack weight->Wb, ow|mw->OWb (A-frag order)
// K index convention: kidx = tap*64 + c  (tap-major, channel minor)
// A-frag (16x16x32): lane l holds A[o = l&15][k = ks*32 + (l>>4)*8 + j]
// -------------------------------------------------------------------------
__global__ __launch_bounds__(256) void prep(
    const float* __restrict__ x, const float* __restrict__ weight,
    const float* __restrict__ ow, const float* __restrict__ mw,
    u16* __restrict__ xt, u16* __restrict__ Wb, u16* __restrict__ OWb)
{
    int i = blockIdx.x, t = threadIdx.x;
    if (i < 1024) {                             // transpose
        __shared__ float tile[64][65];
        int lb = i >> 8;                        // 0..3
        int pix0 = (i & 255) << 6;
        const float* xb = x + ((size_t)lb << 20);
#pragma unroll
        for (int it = 0; it < 4; ++it) {
            int e = it * 256 + t;               // 0..1023
            int c = e >> 4;                     // channel 0..63
            int pl4 = (e & 15) << 2;            // pixel group of 4
            float4 v = *(const float4*)&xb[((size_t)c << 14) + pix0 + pl4];
            tile[c][pl4 + 0] = v.x;
            tile[c][pl4 + 1] = v.y;
            tile[c][pl4 + 2] = v.z;
            tile[c][pl4 + 3] = v.w;
        }
        __syncthreads();
        u16* xo = xt + ((((size_t)lb << 14) + pix0) << 6);
#pragma unroll
        for (int it = 0; it < 4; ++it) {
            int e = it * 256 + t;               // 0..1023
            int c4 = (e & 15) << 2;             // channel group of 4
            int pl = e >> 4;                    // pixel 0..63
            ushort4 v;
            v.x = f2bf(tile[c4 + 0][pl]);
            v.y = f2bf(tile[c4 + 1][pl]);
            v.z = f2bf(tile[c4 + 2][pl]);
            v.w = f2bf(tile[c4 + 3][pl]);
            *(ushort4*)&xo[((size_t)pl << 6) + c4] = v;
        }
    } else {
        int e = (i - 1024) * 256 + t;           // 0..55295
        if (e < 36864) {                        // Wb
            int j = e & 7, ln = (e >> 3) & 63;
            int ks = (e >> 9) % 18, ot = e / 9216;
            int o = ot * 16 + (ln & 15);
            int kidx = ks * 32 + ((ln >> 4) << 3) + j;
            int k = kidx >> 6, c = kidx & 63;
            Wb[e] = f2bf(weight[((size_t)(o * 64 + c)) * 9 + k]);
        } else {                                // OWb
            int e2 = e - 36864;
            int j = e2 & 7, ln = (e2 >> 3) & 63;
            int ks = (e2 >> 9) % 18, ot = e2 / 9216;
            int o = ot * 16 + (ln & 15);
            int kidx = ks * 32 + ((ln >> 4) << 3) + j;
            int k = kidx >> 6, c = kidx & 63;
            float v = 0.0f;
            if (o < 18)      v = ow[((size_t)(o * 64 + c)) * 9 + k];
            else if (o < 27) v = mw[((size_t)((o - 18) * 64 + c)) * 9 + k];
            OWb[e2] = f2bf(v);
        }
    }
}

// -------------------------------------------------------------------------
// fused_dcn: r14 structure (verified best, 44.0 us) with packed-f32 interp.
// Block = 16 pixels (one row segment), 4 waves, 4 barriers:
//   P0 : im2col staging, uint4/lane, oct-fastest -> S swizzled
//   K1 : waves 0,1 (= otile): 18 swizzled ds_read_b128 + 18 MFMA -> param
//   st1: threads 0..143: bilinear corner byte-offsets (int4) + bf16 wts
//   P2 : deformable gather, uint4/lane (8ch), oct-fastest, 2-task batch
//        (8 x 16B loads pinned via sched_barrier) -> S swizzled; tail
//   P3 : wave = otile: 18 swizzled ds_read_b128 + A-frags + MFMA -> out
// LDS: 18432 + 1728 + 2304 + 1152 = 23616 B -> 6 blocks/CU.
// -------------------------------------------------------------------------
__global__ __launch_bounds__(256, 6) void fused_dcn(
    const u16* __restrict__ xt,
    const u16* __restrict__ Wb, const u16* __restrict__ OWb,
    const float* __restrict__ ob, const float* __restrict__ mb,
    float* __restrict__ out)
{
    __shared__ __align__(16) u16 S[16][576];     // 18432 B, group-XOR swizzled
    __shared__ float   param[27][16];            //  1728 B
    __shared__ __align__(16) int4    pwp[144];   //  2304 B corner byte offsets
    __shared__ __align__(16) ushort4 pww[144];   //  1152 B bf16 bilinear*mask wts

    const int t = threadIdx.x;
    const int lane = t & 63;
    const int wv = t >> 6;          // 0..3

    int bid0 = blockIdx.x;          // 4096 blocks
    const int bid = (bid0 & 7) * 512 + (bid0 >> 3);   // XCD swizzle (bijective)
    const int lb = bid >> 10;       // batch
    const int pix0 = (bid & 1023) << 4;
    const int h  = pix0 >> 7;       // 16 pixels share one row
    const int w0 = pix0 & 127;

    const u16* xtb = xt + ((size_t)lb << 20);
    const char* xb8 = (const char*)xtb;

    // ---- P0: im2col staging, uint4/lane, 1152 tasks (144 units x 8 octs) ----
#pragma unroll
    for (int i = 0; i < 4; ++i) {
        int e = i * 256 + t;
        int u = e >> 3, oct = e & 7;
        int k = u >> 4, pixl = u & 15;
        int ky = k / 3, kx = k - 3 * ky;
        int y = h - 1 + ky, xx = w0 + pixl - 1 + kx;
        bool valid = ((unsigned)y < 128u) && ((unsigned)xx < 128u);
        int idx = ((y & 127) << 7) + (xx & 127);
        uint4 v = *(const uint4*)(xtb + ((size_t)idx << 6) + (oct << 3));
        v.x = valid ? v.x : 0u;
        v.y = valid ? v.y : 0u;
        v.z = valid ? v.z : 0u;
        v.w = valid ? v.w : 0u;
        *(uint4*)&S[pixl][k * 64 + ((oct ^ (pixl & 7)) << 3)] = v;
    }
    if (t < 128) {                  // tail: units 128..143 (tap 8 -> ky=2,kx=2)
        int e = 1024 + t;
        int u = e >> 3, oct = e & 7;
        int pixl = u & 15;
        int y = h + 1;
        int xx = w0 + pixl - 1 + 2;
        bool valid = ((unsigned)y < 128u) && ((unsigned)xx < 128u);
        int idx = ((y & 127) << 7) + (xx & 127);
        uint4 v = *(const uint4*)(xtb + ((size_t)idx << 6) + (oct << 3));
        v.x = valid ? v.x : 0u;
        v.y = valid ? v.y : 0u;
        v.z = valid ? v.z : 0u;
        v.w = valid ? v.w : 0u;
        *(uint4*)&S[pixl][8 * 64 + ((oct ^ (pixl & 7)) << 3)] = v;
    }
    __syncthreads();

    // ---- K1: offset/mask conv, waves 0,1 = otile, M=32 x N=16 x K=576 ----
    if (wv < 2) {
        f32x4 k1 = {0.f, 0.f, 0.f, 0.f};
        int brow = lane & 15;
        int hi = lane >> 4;
        int swz = (brow & 7) << 3;
#pragma unroll
        for (int ks = 0; ks < 18; ++ks) {
            short8 a = ((const short8*)OWb)[(wv * 18 + ks) * 64 + lane];
            int coff = ((ks & 1) << 5) + (hi << 3);
            short8 bf = *(const short8*)&S[brow][(ks >> 1) * 64 + (coff ^ swz)];
            k1 = __builtin_amdgcn_mfma_f32_16x16x32_bf16(a, bf, k1, 0, 0, 0);
        }
#pragma unroll
        for (int r = 0; r < 4; ++r) {
            int oc = wv * 16 + (hi << 2) + r;
            if (oc < 18) {
                param[oc][brow] = k1[r] + ob[oc];
            } else if (oc < 27) {
                float s = k1[r] + mb[oc - 18];
                param[oc][brow] = 2.0f / (1.0f + __expf(-s));
            }
        }
    }
    __syncthreads();

    // ---- st1: bilinear corner offsets + weights (threads 0..143) ----
    if (t < 144) {
        int tap = t >> 4, pixl = t & 15;
        int ky = tap / 3, kx = tap - 3 * ky;
        float dy = param[2 * tap][pixl];
        float dx = param[2 * tap + 1][pixl];
        float m  = param[18 + tap][pixl];
        float py = (float)(h - 1 + ky) + dy;
        float px = (float)(w0 + pixl - 1 + kx) + dx;
        float y0f = floorf(py), x0f = floorf(px);
        float fy = py - y0f, fx = px - x0f;
        int y0 = (int)y0f, x0 = (int)x0f;
        int y1 = y0 + 1, x1 = x0 + 1;
        bool vy0 = (unsigned)y0 < (unsigned)H_;
        bool vy1 = (unsigned)y1 < (unsigned)H_;
        bool vx0 = (unsigned)x0 < (unsigned)W_;
        bool vx1 = (unsigned)x1 < (unsigned)W_;
        float w00 = (1.f - fy) * (1.f - fx) * m; if (!(vy0 && vx0)) w00 = 0.f;
        float w01 = (1.f - fy) * fx          * m; if (!(vy0 && vx1)) w01 = 0.f;
        float w10 = fy * (1.f - fx)          * m; if (!(vy1 && vx0)) w10 = 0.f;
        float w11 = fy * fx                   * m; if (!(vy1 && vx1)) w11 = 0.f;
        int y0c = min(max(y0, 0), H_ - 1);
        int y1c = min(max(y1, 0), H_ - 1);
        int x0c = min(max(x0, 0), W_ - 1);
        int x1c = min(max(x1, 0), W_ - 1);
        // byte offsets into xt batch slab: pos (elem) * 64ch * 2B = pos<<7
        pwp[t] = make_int4(((y0c << 7) + x0c) << 7, ((y0c << 7) + x1c) << 7,
                           ((y1c << 7) + x0c) << 7, ((y1c << 7) + x1c) << 7);
        pww[t] = make_ushort4(f2bf(w00), f2bf(w01), f2bf(w10), f2bf(w11));
    }
    __syncthreads();

    // ---- P2: deformable gather, uint4/lane (8ch), 2-task batch ----
    // 8 x 16B corner loads pinned in flight (sched_barrier), then 2 interps.
#pragma unroll
    for (int ii = 0; ii < 2; ++ii) {
        int e0 = ii * 512 + t;
        int e1 = e0 + 256;
        int u0 = e0 >> 3, o0 = e0 & 7;
        int u1 = e1 >> 3, o1 = e1 & 7;
        int4    ofs0 = pwp[u0]; ushort4 wq0 = pww[u0];
        int4    ofs1 = pwp[u1]; ushort4 wq1 = pww[u1];
        int co0 = o0 << 4, co1 = o1 << 4;
        uint4 a00 = *(const uint4*)(xb8 + ofs0.x + co0);
        uint4 a01 = *(const uint4*)(xb8 + ofs0.y + co0);
        uint4 a10 = *(const uint4*)(xb8 + ofs0.z + co0);
        uint4 a11 = *(const uint4*)(xb8 + ofs0.w + co0);
        uint4 b00 = *(const uint4*)(xb8 + ofs1.x + co1);
        uint4 b01 = *(const uint4*)(xb8 + ofs1.y + co1);
        uint4 b10 = *(const uint4*)(xb8 + ofs1.z + co1);
        uint4 b11 = *(const uint4*)(xb8 + ofs1.w + co1);
        __builtin_amdgcn_sched_barrier(0);
        {
            int k = u0 >> 4, pixl = u0 & 15;
            uint4 v = interp8(a00, a01, a10, a11,
                              bf2f(wq0.x), bf2f(wq0.y), bf2f(wq0.z), bf2f(wq0.w));
            *(uint4*)&S[pixl][k * 64 + ((o0 ^ (pixl & 7)) << 3)] = v;
        }
        {
            int k = u1 >> 4, pixl = u1 & 15;
            uint4 v = interp8(b00, b01, b10, b11,
                              bf2f(wq1.x), bf2f(wq1.y), bf2f(wq1.z), bf2f(wq1.w));
            *(uint4*)&S[pixl][k * 64 + ((o1 ^ (pixl & 7)) << 3)] = v;
        }
    }
    if (t < 128) {                  // tail: units 128..143 (tap 8)
        int e = 1024 + t;
        int u = e >> 3, oct = e & 7;
        int pixl = u & 15;
        int4    ofs = pwp[u]; ushort4 wq = pww[u];
        int co = oct << 4;
        uint4 c00 = *(const uint4*)(xb8 + ofs.x + co);
        uint4 c01 = *(const uint4*)(xb8 + ofs.y + co);
        uint4 c10 = *(const uint4*)(xb8 + ofs.z + co);
        uint4 c11 = *(const uint4*)(xb8 + ofs.w + co);
        uint4 v = interp8(c00, c01, c10, c11,
                          bf2f(wq.x), bf2f(wq.y), bf2f(wq.z), bf2f(wq.w));
        *(uint4*)&S[pixl][8 * 64 + ((oct ^ (pixl & 7)) << 3)] = v;
    }
    __syncthreads();

    // ---- P3: main contraction, wave = otile, M=64 x N=16 x K=576 ----
    {
        f32x4 acc = {0.f, 0.f, 0.f, 0.f};
        int brow = lane & 15;
        int hi = lane >> 4;
        int swz = (brow & 7) << 3;
#pragma unroll
        for (int ks = 0; ks < 18; ++ks) {
            int coff = ((ks & 1) << 5) + (hi << 3);
            short8 bfr = *(const short8*)&S[brow][(ks >> 1) * 64 + (coff ^ swz)];
            short8 a = ((const short8*)Wb)[(wv * 18 + ks) * 64 + lane];
            acc = __builtin_amdgcn_mfma_f32_16x16x32_bf16(a, bfr, acc, 0, 0, 0);
        }
        float* op = out + ((size_t)lb << 20) + pix0;
#pragma unroll
        for (int r = 0; r < 4; ++r) {
            int o = wv * 16 + (hi << 2) + r;
            op[((size_t)o << 14) + brow] = acc[r];
        }
    }
}

// -------------------------------------------------------------------------
extern "C" void kernel_launch(void* const* d_in, const int* in_sizes, int n_in,
                              void* d_out, int out_size, void* d_ws, size_t ws_size,
                              hipStream_t stream)
{
    const float* x        = (const float*)d_in[0];
    const float* offset_w = (const float*)d_in[1];
    const float* offset_b = (const float*)d_in[2];
    const float* mod_w    = (const float*)d_in[3];
    const float* mod_b    = (const float*)d_in[4];
    const float* weight   = (const float*)d_in[5];
    float* out = (float*)d_out;

    // Workspace (u16), total ~8.1 MiB:
    //   Wb : 36864 | OWb : 18432 | xt : 4 batches * HW * C = 4,194,304
    u16* Wb  = (u16*)d_ws;
    u16* OWb = Wb + 36864;
    u16* xt  = OWb + 18432;

    prep<<<1240, 256, 0, stream>>>(x, weight, offset_w, mod_w, xt, Wb, OWb);
    fused_dcn<<<4096, 256, 0, stream>>>(xt, Wb, OWb, offset_b, mod_b, out);
}